// Round 1
// baseline (1411.716 us; speedup 1.0000x reference)
//
#include <hip/hip_runtime.h>
#include <stdint.h>

typedef int v4i  __attribute__((ext_vector_type(4)));
typedef int v16i __attribute__((ext_vector_type(16)));

#define T_TOK 8192
#define H_DIM 1024
#define F_DIM 3584
#define N_EXP 8

// ---------------- workspace layout (bytes) ----------------
#define W1Q_OFF   0u
#define W3Q_OFF   29360128u
#define W2Q_OFF   58720256u
#define XQ_OFF    88080384u
#define XS_OFF    96468992u
#define GBUF_OFF  96501760u             // (16384+128) rows * 3584 = 59179008
#define CNT_OFF   155680768u
#define OFFS_OFF  155681024u
#define LIST_OFF  155681280u            // 8*8192*4
#define TW_OFF    155943424u            // 8*8192*4
// total ~156.2 MB

// ---------------- weight fp32 -> int8 conversion ----------------
__global__ __launch_bounds__(256) void convert_w_kernel(
    const float* __restrict__ w1, const float* __restrict__ w3,
    const float* __restrict__ w2, int8_t* __restrict__ o1,
    int8_t* __restrict__ o3, int8_t* __restrict__ o2)
{
    const float* src;
    int8_t* dst;
    if (blockIdx.y == 0)      { src = w1; dst = o1; }
    else if (blockIdx.y == 1) { src = w3; dst = o3; }
    else                      { src = w2; dst = o2; }
    size_t i = (size_t)blockIdx.x * blockDim.x + threadIdx.x;   // float4 index
    float4 v = ((const float4*)src)[i];
    char4 c;
    c.x = (signed char)v.x;  // values are exact ints in [-127,127]
    c.y = (signed char)v.y;
    c.z = (signed char)v.z;
    c.w = (signed char)v.w;
    ((char4*)dst)[i] = c;
}

// ---------------- router + per-token activation quant ----------------
__global__ __launch_bounds__(256) void router_kernel(
    const float* __restrict__ x, const float* __restrict__ gw,
    int8_t* __restrict__ xq, float* __restrict__ xs,
    int* __restrict__ cnt, int* __restrict__ list, float* __restrict__ tw,
    float* __restrict__ logits_out)
{
    const int token = blockIdx.x;
    const int t = threadIdx.x;
    __shared__ float red[256 * 8];
    __shared__ float ram[256];
    __shared__ float s_scale;

    const float4 xv = ((const float4*)(x + (size_t)token * H_DIM))[t];
    float am = fmaxf(fmaxf(fabsf(xv.x), fabsf(xv.y)), fmaxf(fabsf(xv.z), fabsf(xv.w)));
    float part[8];
#pragma unroll
    for (int e = 0; e < 8; e++) {
        const float4 g = ((const float4*)(gw + e * H_DIM))[t];
        part[e] = xv.x * g.x + xv.y * g.y + xv.z * g.z + xv.w * g.w;
    }
#pragma unroll
    for (int e = 0; e < 8; e++) red[t * 8 + e] = part[e];
    ram[t] = am;
    __syncthreads();
    for (int s = 128; s > 0; s >>= 1) {
        if (t < s) {
#pragma unroll
            for (int e = 0; e < 8; e++) red[t * 8 + e] += red[(t + s) * 8 + e];
            ram[t] = fmaxf(ram[t], ram[t + s]);
        }
        __syncthreads();
    }
    if (t == 0) {
        float l[8];
#pragma unroll
        for (int e = 0; e < 8; e++) l[e] = red[e];
        float m = l[0];
#pragma unroll
        for (int e = 1; e < 8; e++) m = fmaxf(m, l[e]);
        float p[8], sum = 0.0f;
#pragma unroll
        for (int e = 0; e < 8; e++) { p[e] = expf(l[e] - m); sum += p[e]; }
#pragma unroll
        for (int e = 0; e < 8; e++) p[e] = p[e] / sum;
        // top-2 (strict > : lowest index wins ties, matches lax.top_k)
        int i0 = 0;
#pragma unroll
        for (int e = 1; e < 8; e++) if (p[e] > p[i0]) i0 = e;
        int i1 = (i0 == 0) ? 1 : 0;
#pragma unroll
        for (int e = 0; e < 8; e++) if (e != i0 && p[e] > p[i1]) i1 = e;
        float tsum = p[i0] + p[i1];
        float w0 = p[i0] / tsum;
        float w1 = p[i1] / tsum;
#pragma unroll
        for (int e = 0; e < 8; e++) logits_out[(size_t)token * 8 + e] = l[e];
        int pos0 = atomicAdd(&cnt[i0], 1);
        list[i0 * T_TOK + pos0] = token;  tw[i0 * T_TOK + pos0] = w0;
        int pos1 = atomicAdd(&cnt[i1], 1);
        list[i1 * T_TOK + pos1] = token;  tw[i1 * T_TOK + pos1] = w1;
        s_scale = fmaxf(ram[0], 1e-8f) / 127.0f;
        xs[token] = s_scale;
    }
    __syncthreads();
    const float s = s_scale;
    char4 c;
    c.x = (signed char)fminf(fmaxf(rintf(xv.x / s), -127.0f), 127.0f);
    c.y = (signed char)fminf(fmaxf(rintf(xv.y / s), -127.0f), 127.0f);
    c.z = (signed char)fminf(fmaxf(rintf(xv.z / s), -127.0f), 127.0f);
    c.w = (signed char)fminf(fmaxf(rintf(xv.w / s), -127.0f), 127.0f);
    ((char4*)xq)[(size_t)token * (H_DIM / 4) + t] = c;
}

// ---------------- prefix offsets ----------------
__global__ void prefix_kernel(const int* __restrict__ cnt, int* __restrict__ offs)
{
    if (threadIdx.x == 0) {
        int s = 0;
#pragma unroll
        for (int e = 0; e < N_EXP; e++) { offs[e] = s; s += cnt[e]; }
    }
}

// ---------------- grouped GEMM1: h1/h3 + SwiGLU + requant ----------------
// block tile: 128 tokens x 128 F-cols (per each of w1,w3), BK=64, 4 waves 2x2
__global__ __launch_bounds__(256, 2) void gemm1_kernel(
    const int8_t* __restrict__ xq, const float* __restrict__ xs,
    const int8_t* __restrict__ w1, const int8_t* __restrict__ w3,
    const float* __restrict__ w1s, const float* __restrict__ w3s,
    const float* __restrict__ dscale,
    const int* __restrict__ cnt, const int* __restrict__ offs,
    const int* __restrict__ list, int8_t* __restrict__ gbuf)
{
    const int e  = blockIdx.x >> 6;
    const int mt = blockIdx.x & 63;
    const int ft = blockIdx.y;
    const int count = cnt[e];
    if (mt * 128 >= count) return;
    const int goff = offs[e];
    const int t = threadIdx.x;
    const int lane = t & 63, wave = t >> 6;
    const int wm = wave >> 1, wn = wave & 1;
    const int* liste = list + e * T_TOK;

    __shared__ v4i sm[1536];   // A: [0,512)  B1: [512,1024)  B3: [1024,1536)

    int tokenA[2];
#pragma unroll
    for (int j = 0; j < 2; j++) {
        int q = t + 256 * j;
        int rr = q >> 2;
        int p = mt * 128 + rr;
        tokenA[j] = (p < count) ? liste[p] : 0;
    }
    const int8_t* w1e = w1 + (size_t)e * F_DIM * H_DIM;
    const int8_t* w3e = w3 + (size_t)e * F_DIM * H_DIM;

    v16i acc1[2][2], acc3[2][2];
#pragma unroll
    for (int i = 0; i < 2; i++)
#pragma unroll
        for (int j = 0; j < 2; j++)
#pragma unroll
            for (int r = 0; r < 16; r++) { acc1[i][j][r] = 0; acc3[i][j][r] = 0; }

    for (int kt = 0; kt < H_DIM / 64; kt++) {
        const int k0 = kt * 64;
#pragma unroll
        for (int j = 0; j < 2; j++) {        // A stage: 512 chunks
            int q = t + 256 * j;
            int c = q & 3, rr = q >> 2;
            v4i val = *(const v4i*)(xq + (size_t)tokenA[j] * H_DIM + k0 + c * 16);
            sm[(rr >> 5) * 128 + c * 32 + (rr & 31)] = val;
        }
#pragma unroll
        for (int j = 0; j < 2; j++) {        // B1+B3 stage: 512 chunks each
            int q = t + 256 * j;
            int c = q & 3, n = q >> 2;
            int f = ft * 128 + n;
            v4i v1 = *(const v4i*)(w1e + (size_t)f * H_DIM + k0 + c * 16);
            v4i v3 = *(const v4i*)(w3e + (size_t)f * H_DIM + k0 + c * 16);
            int dst = (n >> 5) * 128 + c * 32 + (n & 31);
            sm[512 + dst]  = v1;
            sm[1024 + dst] = v3;
        }
        __syncthreads();
#pragma unroll
        for (int ks = 0; ks < 2; ks++) {
            const int cc = 2 * ks + (lane >> 5);
            const int r = lane & 31;
            v4i a0  = sm[(wm * 2 + 0) * 128 + cc * 32 + r];
            v4i a1  = sm[(wm * 2 + 1) * 128 + cc * 32 + r];
            v4i b1a = sm[512 + (wn * 2 + 0) * 128 + cc * 32 + r];
            v4i b1b = sm[512 + (wn * 2 + 1) * 128 + cc * 32 + r];
            v4i b3a = sm[1024 + (wn * 2 + 0) * 128 + cc * 32 + r];
            v4i b3b = sm[1024 + (wn * 2 + 1) * 128 + cc * 32 + r];
            acc1[0][0] = __builtin_amdgcn_mfma_i32_32x32x32_i8(a0, b1a, acc1[0][0], 0, 0, 0);
            acc1[0][1] = __builtin_amdgcn_mfma_i32_32x32x32_i8(a0, b1b, acc1[0][1], 0, 0, 0);
            acc1[1][0] = __builtin_amdgcn_mfma_i32_32x32x32_i8(a1, b1a, acc1[1][0], 0, 0, 0);
            acc1[1][1] = __builtin_amdgcn_mfma_i32_32x32x32_i8(a1, b1b, acc1[1][1], 0, 0, 0);
            acc3[0][0] = __builtin_amdgcn_mfma_i32_32x32x32_i8(a0, b3a, acc3[0][0], 0, 0, 0);
            acc3[0][1] = __builtin_amdgcn_mfma_i32_32x32x32_i8(a0, b3b, acc3[0][1], 0, 0, 0);
            acc3[1][0] = __builtin_amdgcn_mfma_i32_32x32x32_i8(a1, b3a, acc3[1][0], 0, 0, 0);
            acc3[1][1] = __builtin_amdgcn_mfma_i32_32x32x32_i8(a1, b3b, acc3[1][1], 0, 0, 0);
        }
        __syncthreads();
    }

    const float ds = dscale[e];
#pragma unroll
    for (int im = 0; im < 2; im++) {
#pragma unroll
        for (int in = 0; in < 2; in++) {
            const int fcol = ft * 128 + wn * 64 + in * 32 + (lane & 31);
            const float s1 = w1s[e * F_DIM + fcol];
            const float s3 = w3s[e * F_DIM + fcol];
#pragma unroll
            for (int r = 0; r < 16; r++) {
                int row = wm * 64 + im * 32 + (r & 3) + 8 * (r >> 2) + 4 * (lane >> 5);
                int p = mt * 128 + row;
                if (p < count) {
                    int token = liste[p];
                    float sx = xs[token];
                    float h1 = (float)acc1[im][in][r] * sx * s1;
                    float h3 = (float)acc3[im][in][r] * sx * s3;
                    float g = (h1 / (1.0f + expf(-h1))) * h3;
                    float qv = fminf(fmaxf(rintf(g / ds), -127.0f), 127.0f);
                    gbuf[(size_t)(goff + p) * F_DIM + fcol] = (int8_t)qv;
                }
            }
        }
    }
}

// ---------------- grouped GEMM2: down proj + scatter-add ----------------
// block tile: 128 rows x 128 H-cols, K=3584, BK=64
__global__ __launch_bounds__(256, 2) void gemm2_kernel(
    const int8_t* __restrict__ gbuf, const int8_t* __restrict__ w2,
    const float* __restrict__ w2s, const float* __restrict__ dscale,
    const int* __restrict__ cnt, const int* __restrict__ offs,
    const int* __restrict__ list, const float* __restrict__ tw,
    float* __restrict__ out)
{
    const int e  = blockIdx.x >> 6;
    const int mt = blockIdx.x & 63;
    const int ht = blockIdx.y;     // 0..7
    const int count = cnt[e];
    if (mt * 128 >= count) return;
    const int goff = offs[e];
    const int t = threadIdx.x;
    const int lane = t & 63, wave = t >> 6;
    const int wm = wave >> 1, wn = wave & 1;
    const int* liste = list + e * T_TOK;
    const float* twe = tw + e * T_TOK;

    __shared__ v4i sm[1024];   // A: [0,512)  B: [512,1024)

    const int8_t* w2e = w2 + (size_t)e * H_DIM * F_DIM;
    const int8_t* arow = gbuf + (size_t)(goff + mt * 128) * F_DIM;

    v16i acc[2][2];
#pragma unroll
    for (int i = 0; i < 2; i++)
#pragma unroll
        for (int j = 0; j < 2; j++)
#pragma unroll
            for (int r = 0; r < 16; r++) acc[i][j][r] = 0;

    for (int kt = 0; kt < F_DIM / 64; kt++) {
        const int k0 = kt * 64;
#pragma unroll
        for (int j = 0; j < 2; j++) {
            int q = t + 256 * j;
            int c = q & 3, rr = q >> 2;
            // rows past count read (in-bounds) garbage; those acc rows are never written
            v4i va = *(const v4i*)(arow + (size_t)rr * F_DIM + k0 + c * 16);
            int dst = (rr >> 5) * 128 + c * 32 + (rr & 31);
            sm[dst] = va;
            int h = ht * 128 + rr;
            v4i vb = *(const v4i*)(w2e + (size_t)h * F_DIM + k0 + c * 16);
            sm[512 + dst] = vb;
        }
        __syncthreads();
#pragma unroll
        for (int ks = 0; ks < 2; ks++) {
            const int cc = 2 * ks + (lane >> 5);
            const int r = lane & 31;
            v4i a0 = sm[(wm * 2 + 0) * 128 + cc * 32 + r];
            v4i a1 = sm[(wm * 2 + 1) * 128 + cc * 32 + r];
            v4i b0 = sm[512 + (wn * 2 + 0) * 128 + cc * 32 + r];
            v4i b1 = sm[512 + (wn * 2 + 1) * 128 + cc * 32 + r];
            acc[0][0] = __builtin_amdgcn_mfma_i32_32x32x32_i8(a0, b0, acc[0][0], 0, 0, 0);
            acc[0][1] = __builtin_amdgcn_mfma_i32_32x32x32_i8(a0, b1, acc[0][1], 0, 0, 0);
            acc[1][0] = __builtin_amdgcn_mfma_i32_32x32x32_i8(a1, b0, acc[1][0], 0, 0, 0);
            acc[1][1] = __builtin_amdgcn_mfma_i32_32x32x32_i8(a1, b1, acc[1][1], 0, 0, 0);
        }
        __syncthreads();
    }

    const float ds = dscale[e];
#pragma unroll
    for (int im = 0; im < 2; im++) {
#pragma unroll
        for (int in = 0; in < 2; in++) {
            const int h = ht * 128 + wn * 64 + in * 32 + (lane & 31);
            const float sc = ds * w2s[e * H_DIM + h];
#pragma unroll
            for (int r = 0; r < 16; r++) {
                int row = wm * 64 + im * 32 + (r & 3) + 8 * (r >> 2) + 4 * (lane >> 5);
                int p = mt * 128 + row;
                if (p < count) {
                    int token = liste[p];
                    float rw = twe[p];
                    atomicAdd(&out[(size_t)token * H_DIM + h], (float)acc[im][in][r] * sc * rw);
                }
            }
        }
    }
}

extern "C" void kernel_launch(void* const* d_in, const int* in_sizes, int n_in,
                              void* d_out, int out_size, void* d_ws, size_t ws_size,
                              hipStream_t stream)
{
    const float* x    = (const float*)d_in[0];
    const float* gw   = (const float*)d_in[1];
    const float* w1   = (const float*)d_in[2];
    const float* w1s  = (const float*)d_in[3];
    const float* w3   = (const float*)d_in[4];
    const float* w3s  = (const float*)d_in[5];
    const float* w2   = (const float*)d_in[6];
    const float* w2s  = (const float*)d_in[7];
    const float* dsc  = (const float*)d_in[8];

    float* out = (float*)d_out;
    float* logits_out = out + (size_t)T_TOK * H_DIM;

    char* ws = (char*)d_ws;
    int8_t* w1q  = (int8_t*)(ws + W1Q_OFF);
    int8_t* w3q  = (int8_t*)(ws + W3Q_OFF);
    int8_t* w2q  = (int8_t*)(ws + W2Q_OFF);
    int8_t* xq   = (int8_t*)(ws + XQ_OFF);
    float*  xs   = (float*) (ws + XS_OFF);
    int8_t* gbuf = (int8_t*)(ws + GBUF_OFF);
    int*    cnt  = (int*)   (ws + CNT_OFF);
    int*    offs = (int*)   (ws + OFFS_OFF);
    int*    list = (int*)   (ws + LIST_OFF);
    float*  tws  = (float*) (ws + TW_OFF);

    hipMemsetAsync(out, 0, (size_t)T_TOK * H_DIM * sizeof(float), stream);
    hipMemsetAsync(cnt, 0, N_EXP * sizeof(int), stream);

    convert_w_kernel<<<dim3(28672, 3), 256, 0, stream>>>(w1, w3, w2, w1q, w3q, w2q);
    router_kernel<<<T_TOK, 256, 0, stream>>>(x, gw, xq, xs, cnt, list, tws, logits_out);
    prefix_kernel<<<1, 64, 0, stream>>>(cnt, offs);
    gemm1_kernel<<<dim3(N_EXP * 64, F_DIM / 128), 256, 0, stream>>>(
        xq, xs, w1q, w3q, w1s, w3s, dsc, cnt, offs, list, gbuf);
    gemm2_kernel<<<dim3(N_EXP * 64, H_DIM / 128), 256, 0, stream>>>(
        gbuf, w2q, w2s, dsc, cnt, offs, list, tws, out);
}

// Round 2
// 1407.140 us; speedup vs baseline: 1.0033x; 1.0033x over previous
//
#include <hip/hip_runtime.h>
#include <stdint.h>

typedef int v4i  __attribute__((ext_vector_type(4)));
typedef int v16i __attribute__((ext_vector_type(16)));

#define T_TOK 8192
#define H_DIM 1024
#define F_DIM 3584
#define N_EXP 8

// ---------------- workspace layout (bytes) ----------------
// ybuf (67.1 MB) aliases [w1q|w3q|xq|xs] (67.14 MB) — those are dead after gemm1.
#define W1Q_OFF   0u
#define W3Q_OFF   29360128u
#define XQ_OFF    58720256u
#define XS_OFF    67108864u
#define YBUF_OFF  0u
#define W2Q_OFF   67141632u
#define GBUF_OFF  96501760u             // 16512 rows * 3584
#define CNT_OFF   155680768u
#define OFFS_OFF  155681024u
#define LIST_OFF  155681280u            // 8*8192*4
#define TW_OFF    155943424u            // 8*8192*4
#define TSLOT_OFF 156205568u            // 8192*2*4
// total ~156.3 MB

__device__ __forceinline__ void async16(const void* g, void* l) {
    __builtin_amdgcn_global_load_lds(
        (const __attribute__((address_space(1))) unsigned int*)g,
        (__attribute__((address_space(3))) unsigned int*)l, 16, 0, 0);
}

// ---------------- weight fp32 -> int8 conversion ----------------
__global__ __launch_bounds__(256) void convert_w_kernel(
    const float* __restrict__ w1, const float* __restrict__ w3,
    const float* __restrict__ w2, int8_t* __restrict__ o1,
    int8_t* __restrict__ o3, int8_t* __restrict__ o2)
{
    const float* src;
    int8_t* dst;
    if (blockIdx.y == 0)      { src = w1; dst = o1; }
    else if (blockIdx.y == 1) { src = w3; dst = o3; }
    else                      { src = w2; dst = o2; }
    size_t i = (size_t)blockIdx.x * blockDim.x + threadIdx.x;   // float4 index
    float4 v = ((const float4*)src)[i];
    char4 c;
    c.x = (signed char)v.x;  // values are exact ints in [-127,127]
    c.y = (signed char)v.y;
    c.z = (signed char)v.z;
    c.w = (signed char)v.w;
    ((char4*)dst)[i] = c;
}

// ---------------- router + per-token activation quant ----------------
__global__ __launch_bounds__(256) void router_kernel(
    const float* __restrict__ x, const float* __restrict__ gw,
    int8_t* __restrict__ xq, float* __restrict__ xs,
    int* __restrict__ cnt, int* __restrict__ list, float* __restrict__ tw,
    int* __restrict__ tslot, float* __restrict__ logits_out)
{
    const int token = blockIdx.x;
    const int t = threadIdx.x;
    __shared__ float red[256 * 8];
    __shared__ float ram[256];
    __shared__ float s_scale;

    const float4 xv = ((const float4*)(x + (size_t)token * H_DIM))[t];
    float am = fmaxf(fmaxf(fabsf(xv.x), fabsf(xv.y)), fmaxf(fabsf(xv.z), fabsf(xv.w)));
    float part[8];
#pragma unroll
    for (int e = 0; e < 8; e++) {
        const float4 g = ((const float4*)(gw + e * H_DIM))[t];
        part[e] = xv.x * g.x + xv.y * g.y + xv.z * g.z + xv.w * g.w;
    }
#pragma unroll
    for (int e = 0; e < 8; e++) red[t * 8 + e] = part[e];
    ram[t] = am;
    __syncthreads();
    for (int s = 128; s > 0; s >>= 1) {
        if (t < s) {
#pragma unroll
            for (int e = 0; e < 8; e++) red[t * 8 + e] += red[(t + s) * 8 + e];
            ram[t] = fmaxf(ram[t], ram[t + s]);
        }
        __syncthreads();
    }
    if (t == 0) {
        float l[8];
#pragma unroll
        for (int e = 0; e < 8; e++) l[e] = red[e];
        float m = l[0];
#pragma unroll
        for (int e = 1; e < 8; e++) m = fmaxf(m, l[e]);
        float p[8], sum = 0.0f;
#pragma unroll
        for (int e = 0; e < 8; e++) { p[e] = expf(l[e] - m); sum += p[e]; }
#pragma unroll
        for (int e = 0; e < 8; e++) p[e] = p[e] / sum;
        // top-2 (strict > : lowest index wins ties, matches lax.top_k)
        int i0 = 0;
#pragma unroll
        for (int e = 1; e < 8; e++) if (p[e] > p[i0]) i0 = e;
        int i1 = (i0 == 0) ? 1 : 0;
#pragma unroll
        for (int e = 0; e < 8; e++) if (e != i0 && p[e] > p[i1]) i1 = e;
        float tsum = p[i0] + p[i1];
        float w0 = p[i0] / tsum;
        float w1 = p[i1] / tsum;
#pragma unroll
        for (int e = 0; e < 8; e++) logits_out[(size_t)token * 8 + e] = l[e];
        int pos0 = atomicAdd(&cnt[i0], 1);
        list[i0 * T_TOK + pos0] = token;  tw[i0 * T_TOK + pos0] = w0;
        int pos1 = atomicAdd(&cnt[i1], 1);
        list[i1 * T_TOK + pos1] = token;  tw[i1 * T_TOK + pos1] = w1;
        tslot[token * 2 + 0] = (i0 << 16) | pos0;
        tslot[token * 2 + 1] = (i1 << 16) | pos1;
        s_scale = fmaxf(ram[0], 1e-8f) / 127.0f;
        xs[token] = s_scale;
    }
    __syncthreads();
    const float s = s_scale;
    char4 c;
    c.x = (signed char)fminf(fmaxf(rintf(xv.x / s), -127.0f), 127.0f);
    c.y = (signed char)fminf(fmaxf(rintf(xv.y / s), -127.0f), 127.0f);
    c.z = (signed char)fminf(fmaxf(rintf(xv.z / s), -127.0f), 127.0f);
    c.w = (signed char)fminf(fmaxf(rintf(xv.w / s), -127.0f), 127.0f);
    ((char4*)xq)[(size_t)token * (H_DIM / 4) + t] = c;
}

// ---------------- prefix offsets ----------------
__global__ void prefix_kernel(const int* __restrict__ cnt, int* __restrict__ offs)
{
    if (threadIdx.x == 0) {
        int s = 0;
#pragma unroll
        for (int e = 0; e < N_EXP; e++) { offs[e] = s; s += cnt[e]; }
    }
}

// ---------------- grouped GEMM1: h1/h3 + SwiGLU + requant ----------------
// block tile: 128 tokens x 128 F-cols (w1 and w3), BK=64, 4 waves 2x2.
// Staging via global_load_lds dwordx4: LDS slot = wave*128 + j*64 + lane,
// which decodes to (row = wave*32 + (lane&31), kchunk = j*2 + (lane>>5)) —
// identical chunk-major layout the MFMA ds_read_b128 fragment reads expect.
__global__ __launch_bounds__(256, 2) void gemm1_kernel(
    const int8_t* __restrict__ xq, const float* __restrict__ xs,
    const int8_t* __restrict__ w1, const int8_t* __restrict__ w3,
    const float* __restrict__ w1s, const float* __restrict__ w3s,
    const float* __restrict__ dscale,
    const int* __restrict__ cnt, const int* __restrict__ offs,
    const int* __restrict__ list, int8_t* __restrict__ gbuf)
{
    const int e  = blockIdx.x >> 6;
    const int mt = blockIdx.x & 63;
    const int ft = blockIdx.y;
    const int count = cnt[e];
    if (mt * 128 >= count) return;
    const int goff = offs[e];
    const int t = threadIdx.x;
    const int lane = t & 63, wave = t >> 6;
    const int wm = wave >> 1, wn = wave & 1;
    const int* liste = list + e * T_TOK;

    __shared__ v4i sm[1536];   // A: [0,512)  B1: [512,1024)  B3: [1024,1536)

    const int8_t* w1e = w1 + (size_t)e * F_DIM * H_DIM;
    const int8_t* w3e = w3 + (size_t)e * F_DIM * H_DIM;

    // per-thread DMA source descriptors
    const int rA = wave * 32 + (lane & 31);
    const int pA = mt * 128 + rA;
    const int tokA = liste[pA < count ? pA : 0];
    const int csel = (lane >> 5) * 16;                 // byte offset within BK
    const int8_t* gA  = xq  + (size_t)tokA * H_DIM + csel;
    const int fB = ft * 128 + rA;
    const int8_t* gB1 = w1e + (size_t)fB * H_DIM + csel;
    const int8_t* gB3 = w3e + (size_t)fB * H_DIM + csel;
    v4i* lA  = &sm[wave * 128];
    v4i* lB1 = &sm[512 + wave * 128];
    v4i* lB3 = &sm[1024 + wave * 128];

    v16i acc1[2][2], acc3[2][2];
#pragma unroll
    for (int i = 0; i < 2; i++)
#pragma unroll
        for (int j = 0; j < 2; j++)
#pragma unroll
            for (int r = 0; r < 16; r++) { acc1[i][j][r] = 0; acc3[i][j][r] = 0; }

    for (int kt = 0; kt < H_DIM / 64; kt++) {
        const int ko = kt * 64;
        async16(gA  + ko,      lA);
        async16(gA  + ko + 32, lA  + 64);
        async16(gB1 + ko,      lB1);
        async16(gB1 + ko + 32, lB1 + 64);
        async16(gB3 + ko,      lB3);
        async16(gB3 + ko + 32, lB3 + 64);
        __syncthreads();
#pragma unroll
        for (int ks = 0; ks < 2; ks++) {
            const int cc = 2 * ks + (lane >> 5);
            const int r = lane & 31;
            v4i a0  = sm[(wm * 2 + 0) * 128 + cc * 32 + r];
            v4i a1  = sm[(wm * 2 + 1) * 128 + cc * 32 + r];
            v4i b1a = sm[512 + (wn * 2 + 0) * 128 + cc * 32 + r];
            v4i b1b = sm[512 + (wn * 2 + 1) * 128 + cc * 32 + r];
            v4i b3a = sm[1024 + (wn * 2 + 0) * 128 + cc * 32 + r];
            v4i b3b = sm[1024 + (wn * 2 + 1) * 128 + cc * 32 + r];
            acc1[0][0] = __builtin_amdgcn_mfma_i32_32x32x32_i8(a0, b1a, acc1[0][0], 0, 0, 0);
            acc1[0][1] = __builtin_amdgcn_mfma_i32_32x32x32_i8(a0, b1b, acc1[0][1], 0, 0, 0);
            acc1[1][0] = __builtin_amdgcn_mfma_i32_32x32x32_i8(a1, b1a, acc1[1][0], 0, 0, 0);
            acc1[1][1] = __builtin_amdgcn_mfma_i32_32x32x32_i8(a1, b1b, acc1[1][1], 0, 0, 0);
            acc3[0][0] = __builtin_amdgcn_mfma_i32_32x32x32_i8(a0, b3a, acc3[0][0], 0, 0, 0);
            acc3[0][1] = __builtin_amdgcn_mfma_i32_32x32x32_i8(a0, b3b, acc3[0][1], 0, 0, 0);
            acc3[1][0] = __builtin_amdgcn_mfma_i32_32x32x32_i8(a1, b3a, acc3[1][0], 0, 0, 0);
            acc3[1][1] = __builtin_amdgcn_mfma_i32_32x32x32_i8(a1, b3b, acc3[1][1], 0, 0, 0);
        }
        __syncthreads();
    }

    const float ds = dscale[e];
#pragma unroll
    for (int im = 0; im < 2; im++) {
#pragma unroll
        for (int in = 0; in < 2; in++) {
            const int fcol = ft * 128 + wn * 64 + in * 32 + (lane & 31);
            const float s1 = w1s[e * F_DIM + fcol];
            const float s3 = w3s[e * F_DIM + fcol];
#pragma unroll
            for (int r = 0; r < 16; r++) {
                int row = wm * 64 + im * 32 + (r & 3) + 8 * (r >> 2) + 4 * (lane >> 5);
                int p = mt * 128 + row;
                if (p < count) {
                    int token = liste[p];
                    float sx = xs[token];
                    float h1 = (float)acc1[im][in][r] * sx * s1;
                    float h3 = (float)acc3[im][in][r] * sx * s3;
                    float g = (h1 / (1.0f + expf(-h1))) * h3;
                    float qv = fminf(fmaxf(rintf(g / ds), -127.0f), 127.0f);
                    gbuf[(size_t)(goff + p) * F_DIM + fcol] = (int8_t)qv;
                }
            }
        }
    }
}

// ---------------- grouped GEMM2: down proj -> ybuf (no atomics) ----------------
__global__ __launch_bounds__(256, 2) void gemm2_kernel(
    const int8_t* __restrict__ gbuf, const int8_t* __restrict__ w2,
    const float* __restrict__ w2s, const float* __restrict__ dscale,
    const int* __restrict__ cnt, const int* __restrict__ offs,
    const int* __restrict__ list, const float* __restrict__ tw,
    float* __restrict__ ybuf)
{
    const int e  = blockIdx.x >> 6;
    const int mt = blockIdx.x & 63;
    const int ht = blockIdx.y;     // 0..7
    const int count = cnt[e];
    if (mt * 128 >= count) return;
    const int goff = offs[e];
    const int t = threadIdx.x;
    const int lane = t & 63, wave = t >> 6;
    const int wm = wave >> 1, wn = wave & 1;
    const float* twe = tw + e * T_TOK;

    __shared__ v4i sm[1024];   // A: [0,512)  B: [512,1024)

    const int8_t* w2e = w2 + (size_t)e * H_DIM * F_DIM;

    const int rA = wave * 32 + (lane & 31);
    const int csel = (lane >> 5) * 16;
    // rows past count read in-bounds garbage (gbuf has +128 row pad); never written out
    const int8_t* gA = gbuf + (size_t)(goff + mt * 128 + rA) * F_DIM + csel;
    const int hB = ht * 128 + rA;
    const int8_t* gB = w2e + (size_t)hB * F_DIM + csel;
    v4i* lA = &sm[wave * 128];
    v4i* lB = &sm[512 + wave * 128];

    v16i acc[2][2];
#pragma unroll
    for (int i = 0; i < 2; i++)
#pragma unroll
        for (int j = 0; j < 2; j++)
#pragma unroll
            for (int r = 0; r < 16; r++) acc[i][j][r] = 0;

    for (int kt = 0; kt < F_DIM / 64; kt++) {
        const int ko = kt * 64;
        async16(gA + ko,      lA);
        async16(gA + ko + 32, lA + 64);
        async16(gB + ko,      lB);
        async16(gB + ko + 32, lB + 64);
        __syncthreads();
#pragma unroll
        for (int ks = 0; ks < 2; ks++) {
            const int cc = 2 * ks + (lane >> 5);
            const int r = lane & 31;
            v4i a0 = sm[(wm * 2 + 0) * 128 + cc * 32 + r];
            v4i a1 = sm[(wm * 2 + 1) * 128 + cc * 32 + r];
            v4i b0 = sm[512 + (wn * 2 + 0) * 128 + cc * 32 + r];
            v4i b1 = sm[512 + (wn * 2 + 1) * 128 + cc * 32 + r];
            acc[0][0] = __builtin_amdgcn_mfma_i32_32x32x32_i8(a0, b0, acc[0][0], 0, 0, 0);
            acc[0][1] = __builtin_amdgcn_mfma_i32_32x32x32_i8(a0, b1, acc[0][1], 0, 0, 0);
            acc[1][0] = __builtin_amdgcn_mfma_i32_32x32x32_i8(a1, b0, acc[1][0], 0, 0, 0);
            acc[1][1] = __builtin_amdgcn_mfma_i32_32x32x32_i8(a1, b1, acc[1][1], 0, 0, 0);
        }
        __syncthreads();
    }

    const float ds = dscale[e];
#pragma unroll
    for (int im = 0; im < 2; im++) {
#pragma unroll
        for (int in = 0; in < 2; in++) {
            const int h = ht * 128 + wn * 64 + in * 32 + (lane & 31);
            const float sc = ds * w2s[e * H_DIM + h];
#pragma unroll
            for (int r = 0; r < 16; r++) {
                int row = wm * 64 + im * 32 + (r & 3) + 8 * (r >> 2) + 4 * (lane >> 5);
                int p = mt * 128 + row;
                if (p < count) {
                    float rw = twe[p];   // route weight folded in here
                    ybuf[(size_t)(goff + p) * H_DIM + h] = (float)acc[im][in][r] * sc * rw;
                }
            }
        }
    }
}

// ---------------- combine: out[token] = y[slot0] + y[slot1] ----------------
__global__ __launch_bounds__(256) void combine_kernel(
    const float* __restrict__ ybuf, const int* __restrict__ offs,
    const int* __restrict__ tslot, float* __restrict__ out)
{
    const int token = blockIdx.x;
    const int i = threadIdx.x;
    const int s0 = tslot[token * 2 + 0];
    const int s1 = tslot[token * 2 + 1];
    const int slot0 = offs[s0 >> 16] + (s0 & 0xffff);
    const int slot1 = offs[s1 >> 16] + (s1 & 0xffff);
    float4 a = ((const float4*)(ybuf + (size_t)slot0 * H_DIM))[i];
    float4 b = ((const float4*)(ybuf + (size_t)slot1 * H_DIM))[i];
    float4 o;
    o.x = a.x + b.x; o.y = a.y + b.y; o.z = a.z + b.z; o.w = a.w + b.w;
    ((float4*)(out + (size_t)token * H_DIM))[i] = o;
}

extern "C" void kernel_launch(void* const* d_in, const int* in_sizes, int n_in,
                              void* d_out, int out_size, void* d_ws, size_t ws_size,
                              hipStream_t stream)
{
    const float* x    = (const float*)d_in[0];
    const float* gw   = (const float*)d_in[1];
    const float* w1   = (const float*)d_in[2];
    const float* w1s  = (const float*)d_in[3];
    const float* w3   = (const float*)d_in[4];
    const float* w3s  = (const float*)d_in[5];
    const float* w2   = (const float*)d_in[6];
    const float* w2s  = (const float*)d_in[7];
    const float* dsc  = (const float*)d_in[8];

    float* out = (float*)d_out;
    float* logits_out = out + (size_t)T_TOK * H_DIM;

    char* ws = (char*)d_ws;
    int8_t* w1q  = (int8_t*)(ws + W1Q_OFF);
    int8_t* w3q  = (int8_t*)(ws + W3Q_OFF);
    int8_t* w2q  = (int8_t*)(ws + W2Q_OFF);
    int8_t* xq   = (int8_t*)(ws + XQ_OFF);
    float*  xs   = (float*) (ws + XS_OFF);
    float*  ybuf = (float*) (ws + YBUF_OFF);
    int8_t* gbuf = (int8_t*)(ws + GBUF_OFF);
    int*    cnt  = (int*)   (ws + CNT_OFF);
    int*    offs = (int*)   (ws + OFFS_OFF);
    int*    list = (int*)   (ws + LIST_OFF);
    float*  tws  = (float*) (ws + TW_OFF);
    int*    tslot= (int*)   (ws + TSLOT_OFF);

    hipMemsetAsync(cnt, 0, N_EXP * sizeof(int), stream);

    convert_w_kernel<<<dim3(28672, 3), 256, 0, stream>>>(w1, w3, w2, w1q, w3q, w2q);
    router_kernel<<<T_TOK, 256, 0, stream>>>(x, gw, xq, xs, cnt, list, tws, tslot, logits_out);
    prefix_kernel<<<1, 64, 0, stream>>>(cnt, offs);
    gemm1_kernel<<<dim3(N_EXP * 64, F_DIM / 128), 256, 0, stream>>>(
        xq, xs, w1q, w3q, w1s, w3s, dsc, cnt, offs, list, gbuf);
    gemm2_kernel<<<dim3(N_EXP * 64, H_DIM / 128), 256, 0, stream>>>(
        gbuf, w2q, w2s, dsc, cnt, offs, list, tws, ybuf);
    combine_kernel<<<T_TOK, 256, 0, stream>>>(ybuf, offs, tslot, out);
}

// Round 3
// 1001.257 us; speedup vs baseline: 1.4099x; 1.4054x over previous
//
#include <hip/hip_runtime.h>
#include <stdint.h>

typedef int v4i  __attribute__((ext_vector_type(4)));
typedef int v16i __attribute__((ext_vector_type(16)));

#define T_TOK 8192
#define H_DIM 1024
#define F_DIM 3584
#define N_EXP 8

// ---------------- workspace layout (bytes) ----------------
// Tiled ("MFMA-native") layouts: a 16KB slab = [kk(2)][rowgrp(4)][k16(4)][row&31(32)][16B],
// i.e. v4i index kk*512 + rg*128 + k16*32 + r. Staging a slab is a LINEAR copy.
#define W13T_OFF  0u               // [e][ft(28)][kt(8)][mat(2)][16KB] = 58,720,256
#define XQ_OFF    58720256u        // [token][1024]                     8,388,608
#define W2T_OFF   67108864u        // [e][ht(8)][kt(28)][16KB]         29,360,128
#define GBT_OFF   96501760u        // [tile(136)][kt(28)][16KB]        62,390,272
#define XS_OFF    158892032u       // 8192*4
#define LIST_OFF  158924800u       // 8*8192*4
#define TW_OFF    159186944u       // 8*8192*4
#define TSLOT_OFF 159449088u       // 8192*2*4
#define CNT_OFF   159514624u
#define OFFS_OFF  159514656u
#define NT_OFF    159514688u
#define WLIST_OFF 159514752u       // 136*4
// YBUF aliases [w13t|xq] = 67,108,864 B exactly (16384 rows x 4KB); both dead after gemm1.
#define YBUF_OFF  0u
// total ~159.52 MB

__device__ __forceinline__ void async16(const void* g, void* l) {
    __builtin_amdgcn_global_load_lds(
        (const __attribute__((address_space(1))) unsigned int*)g,
        (__attribute__((address_space(3))) unsigned int*)l, 16, 0, 0);
}

__device__ __forceinline__ int pack4(float a, float b, float c, float d) {
    int ia = (int)(signed char)(int)a, ib = (int)(signed char)(int)b;
    int ic = (int)(signed char)(int)c, id = (int)(signed char)(int)d;
    return (ia & 0xff) | ((ib & 0xff) << 8) | ((ic & 0xff) << 16) | (id << 24);
}

// ---------------- weight fp32 -> int8 tiled repack ----------------
// dst-coalesced: thread writes one v4i (16 int8), reads 64B from source row.
__global__ __launch_bounds__(256) void convert_kernel(
    const float* __restrict__ w1, const float* __restrict__ w3,
    const float* __restrict__ w2, v4i* __restrict__ w13t, v4i* __restrict__ w2t)
{
    const int bid = blockIdx.x;
    const float* s;
    v4i* dst;
    if (bid < 14336) {                        // w13t: 3,670,016 v4i
        int d = bid * 256 + threadIdx.x;
        int wi = d & 1023, tile = d >> 10;
        int kk = wi >> 9, rg = (wi >> 7) & 3, k16 = (wi >> 5) & 3, r = wi & 31;
        int mat = tile & 1, kt = (tile >> 1) & 7, rest = tile >> 4;  // e*28+ft
        int e = rest / 28, ft = rest - e * 28;
        s = (mat ? w3 : w1)
          + ((size_t)(e * F_DIM + ft * 128 + rg * 32 + r)) * H_DIM
          + kt * 128 + kk * 64 + k16 * 16;
        dst = w13t + d;
    } else {                                  // w2t: 1,835,008 v4i
        int d = (bid - 14336) * 256 + threadIdx.x;
        int wi = d & 1023, tile = d >> 10;
        int kk = wi >> 9, rg = (wi >> 7) & 3, k16 = (wi >> 5) & 3, r = wi & 31;
        int kt = tile % 28, q = tile / 28;    // (e*8+ht)*28+kt
        int ht = q & 7, e = q >> 3;
        s = w2 + ((size_t)(e * H_DIM + ht * 128 + rg * 32 + r)) * F_DIM
              + kt * 128 + kk * 64 + k16 * 16;
        dst = w2t + d;
    }
    const float4* sv = (const float4*)s;
    float4 f0 = sv[0], f1 = sv[1], f2 = sv[2], f3 = sv[3];
    v4i o;
    o.x = pack4(f0.x, f0.y, f0.z, f0.w);
    o.y = pack4(f1.x, f1.y, f1.z, f1.w);
    o.z = pack4(f2.x, f2.y, f2.z, f2.w);
    o.w = pack4(f3.x, f3.y, f3.z, f3.w);
    *dst = o;
}

// ---------------- router + per-token activation quant ----------------
__global__ __launch_bounds__(256) void router_kernel(
    const float* __restrict__ x, const float* __restrict__ gw,
    int8_t* __restrict__ xq, float* __restrict__ xs,
    int* __restrict__ cnt, int* __restrict__ list, float* __restrict__ tw,
    int* __restrict__ tslot, float* __restrict__ logits_out)
{
    const int token = blockIdx.x;
    const int t = threadIdx.x;
    __shared__ float red[256 * 8];
    __shared__ float ram[256];
    __shared__ float s_scale;

    const float4 xv = ((const float4*)(x + (size_t)token * H_DIM))[t];
    float am = fmaxf(fmaxf(fabsf(xv.x), fabsf(xv.y)), fmaxf(fabsf(xv.z), fabsf(xv.w)));
    float part[8];
#pragma unroll
    for (int e = 0; e < 8; e++) {
        const float4 g = ((const float4*)(gw + e * H_DIM))[t];
        part[e] = xv.x * g.x + xv.y * g.y + xv.z * g.z + xv.w * g.w;
    }
#pragma unroll
    for (int e = 0; e < 8; e++) red[t * 8 + e] = part[e];
    ram[t] = am;
    __syncthreads();
    for (int s = 128; s > 0; s >>= 1) {
        if (t < s) {
#pragma unroll
            for (int e = 0; e < 8; e++) red[t * 8 + e] += red[(t + s) * 8 + e];
            ram[t] = fmaxf(ram[t], ram[t + s]);
        }
        __syncthreads();
    }
    if (t == 0) {
        float l[8];
#pragma unroll
        for (int e = 0; e < 8; e++) l[e] = red[e];
        float m = l[0];
#pragma unroll
        for (int e = 1; e < 8; e++) m = fmaxf(m, l[e]);
        float p[8], sum = 0.0f;
#pragma unroll
        for (int e = 0; e < 8; e++) { p[e] = expf(l[e] - m); sum += p[e]; }
#pragma unroll
        for (int e = 0; e < 8; e++) p[e] = p[e] / sum;
        int i0 = 0;
#pragma unroll
        for (int e = 1; e < 8; e++) if (p[e] > p[i0]) i0 = e;
        int i1 = (i0 == 0) ? 1 : 0;
#pragma unroll
        for (int e = 0; e < 8; e++) if (e != i0 && p[e] > p[i1]) i1 = e;
        float tsum = p[i0] + p[i1];
        float w0 = p[i0] / tsum;
        float w1 = p[i1] / tsum;
#pragma unroll
        for (int e = 0; e < 8; e++) logits_out[(size_t)token * 8 + e] = l[e];
        int pos0 = atomicAdd(&cnt[i0], 1);
        list[i0 * T_TOK + pos0] = token;  tw[i0 * T_TOK + pos0] = w0;
        int pos1 = atomicAdd(&cnt[i1], 1);
        list[i1 * T_TOK + pos1] = token;  tw[i1 * T_TOK + pos1] = w1;
        tslot[token * 2 + 0] = (i0 << 16) | pos0;
        tslot[token * 2 + 1] = (i1 << 16) | pos1;
        s_scale = fmaxf(ram[0], 1e-8f) / 127.0f;
        xs[token] = s_scale;
    }
    __syncthreads();
    const float s = s_scale;
    char4 c;
    c.x = (signed char)fminf(fmaxf(rintf(xv.x / s), -127.0f), 127.0f);
    c.y = (signed char)fminf(fmaxf(rintf(xv.y / s), -127.0f), 127.0f);
    c.z = (signed char)fminf(fmaxf(rintf(xv.z / s), -127.0f), 127.0f);
    c.w = (signed char)fminf(fmaxf(rintf(xv.w / s), -127.0f), 127.0f);
    ((char4*)xq)[(size_t)token * (H_DIM / 4) + t] = c;
}

// ---------------- planner: slot prefix + compact tile worklist ----------------
__global__ void planner_kernel(const int* __restrict__ cnt, int* __restrict__ offs,
                               int* __restrict__ ntile, int* __restrict__ wlist)
{
    if (threadIdx.x == 0) {
        int s = 0, nt = 0;
        for (int e = 0; e < N_EXP; e++) {
            offs[e] = s;
            int c = cnt[e];
            s += c;
            int tc = (c + 127) >> 7;
            for (int m = 0; m < tc; m++) wlist[nt++] = (e << 8) | m;
        }
        *ntile = nt;
    }
}

// ---------------- grouped GEMM1: h1/h3 + SwiGLU + requant -> tiled gbuf ----------------
// 128 tokens x 128 F-cols (w1 and w3), BK=128, 4 waves 2x2. B staging = linear copy.
__global__ __launch_bounds__(256, 2) void gemm1_kernel(
    const int8_t* __restrict__ xq, const float* __restrict__ xs,
    const v4i* __restrict__ w13t,
    const float* __restrict__ w1s, const float* __restrict__ w3s,
    const float* __restrict__ dscale,
    const int* __restrict__ cnt, const int* __restrict__ ntile_p,
    const int* __restrict__ wlist, const int* __restrict__ list,
    int8_t* __restrict__ gbt)
{
    const int bx = blockIdx.x;
    if (bx >= *ntile_p) return;
    const int wl = wlist[bx];
    const int e = wl >> 8, mt = wl & 255;
    const int ft = blockIdx.y;
    const int count = cnt[e];
    const int t = threadIdx.x, lane = t & 63, w = t >> 6;
    const int wm = w >> 1, wn = w & 1;
    const int* liste = list + e * T_TOK;

    __shared__ v4i sm[3072];   // A [0,1024), B1 [1024,2048), B3 [2048,3072)
    char* smb = (char*)sm;

    // A-gather descriptors: chunks cid = w*4+j ; kk=w>>1, rg=(w&1)*2+(j>>1), k16h=j&1
    const int rbase = ((w & 1) * 2) * 32 + (lane & 31);
    const int cm1 = count - 1;
    int p0 = mt * 128 + rbase, p1 = p0 + 32;
    const int tok0 = liste[p0 < count ? p0 : cm1];
    const int tok1 = liste[p1 < count ? p1 : cm1];
    const int aoff = (w >> 1) * 64 + (lane >> 5) * 16;
    const int8_t* gA0 = xq + (size_t)tok0 * H_DIM + aoff;
    const int8_t* gA1 = xq + (size_t)tok1 * H_DIM + aoff;

    // B: tile (e,ft,kt) is 2048 v4i, linear
    const v4i* wb = w13t + (size_t)(e * 28 + ft) * 8 * 2048;
    const int cidb = w * 8;

    v16i acc1[2][2], acc3[2][2];
#pragma unroll
    for (int i = 0; i < 2; i++)
#pragma unroll
        for (int j = 0; j < 2; j++)
#pragma unroll
            for (int r = 0; r < 16; r++) { acc1[i][j][r] = 0; acc3[i][j][r] = 0; }

    for (int kt = 0; kt < 8; kt++) {
        const int ko = kt * 128;
        async16(gA0 + ko,      smb + (w * 4 + 0) * 1024);
        async16(gA0 + ko + 32, smb + (w * 4 + 1) * 1024);
        async16(gA1 + ko,      smb + (w * 4 + 2) * 1024);
        async16(gA1 + ko + 32, smb + (w * 4 + 3) * 1024);
        const char* bsrc = (const char*)(wb + (size_t)kt * 2048) + lane * 16;
#pragma unroll
        for (int j = 0; j < 8; j++)
            async16(bsrc + (cidb + j) * 1024, smb + 16384 + (cidb + j) * 1024);
        __syncthreads();
#pragma unroll
        for (int s = 0; s < 4; s++) {
            const int c16 = (2 * s + (lane >> 5)) & 3;
            const int base = (s >> 1) * 512 + c16 * 32 + (lane & 31);
            v4i a0  = sm[base + (wm * 2 + 0) * 128];
            v4i a1  = sm[base + (wm * 2 + 1) * 128];
            v4i b1a = sm[1024 + base + (wn * 2 + 0) * 128];
            v4i b1b = sm[1024 + base + (wn * 2 + 1) * 128];
            v4i b3a = sm[2048 + base + (wn * 2 + 0) * 128];
            v4i b3b = sm[2048 + base + (wn * 2 + 1) * 128];
            acc1[0][0] = __builtin_amdgcn_mfma_i32_32x32x32_i8(a0, b1a, acc1[0][0], 0, 0, 0);
            acc1[0][1] = __builtin_amdgcn_mfma_i32_32x32x32_i8(a0, b1b, acc1[0][1], 0, 0, 0);
            acc1[1][0] = __builtin_amdgcn_mfma_i32_32x32x32_i8(a1, b1a, acc1[1][0], 0, 0, 0);
            acc1[1][1] = __builtin_amdgcn_mfma_i32_32x32x32_i8(a1, b1b, acc1[1][1], 0, 0, 0);
            acc3[0][0] = __builtin_amdgcn_mfma_i32_32x32x32_i8(a0, b3a, acc3[0][0], 0, 0, 0);
            acc3[0][1] = __builtin_amdgcn_mfma_i32_32x32x32_i8(a0, b3b, acc3[0][1], 0, 0, 0);
            acc3[1][0] = __builtin_amdgcn_mfma_i32_32x32x32_i8(a1, b3a, acc3[1][0], 0, 0, 0);
            acc3[1][1] = __builtin_amdgcn_mfma_i32_32x32x32_i8(a1, b3b, acc3[1][1], 0, 0, 0);
        }
        __syncthreads();
    }

    const float ds = dscale[e];
    // tile bx's K-slab for gemm2 iteration kt=ft starts here (16KB, tiled layout)
    int8_t* gout = gbt + (size_t)bx * 458752 + (size_t)ft * 16384;
#pragma unroll
    for (int im = 0; im < 2; im++) {
#pragma unroll
        for (int in = 0; in < 2; in++) {
            const int fc = wn * 64 + in * 32 + (lane & 31);   // col within 128-wide tile
            const int fcol = ft * 128 + fc;
            const float s1 = w1s[e * F_DIM + fcol];
            const float s3 = w3s[e * F_DIM + fcol];
            const int doff = ((fc >> 6) & 1) * 8192 + ((fc >> 4) & 3) * 512 + (fc & 15);
#pragma unroll
            for (int r = 0; r < 16; r++) {
                int row = wm * 64 + im * 32 + (r & 3) + 8 * (r >> 2) + 4 * (lane >> 5);
                int p = mt * 128 + row;
                if (p < count) {
                    int token = liste[p];
                    float sx = xs[token];
                    float h1 = (float)acc1[im][in][r] * sx * s1;
                    float h3 = (float)acc3[im][in][r] * sx * s3;
                    float g = (h1 / (1.0f + expf(-h1))) * h3;
                    float qv = fminf(fmaxf(rintf(g / ds), -127.0f), 127.0f);
                    gout[doff + (row >> 5) * 2048 + (row & 31) * 16] = (int8_t)qv;
                }
            }
        }
    }
}

// ---------------- grouped GEMM2: down proj -> ybuf (all-linear staging) ----------------
__global__ __launch_bounds__(256, 2) void gemm2_kernel(
    const int8_t* __restrict__ gbt, const v4i* __restrict__ w2t,
    const float* __restrict__ w2s, const float* __restrict__ dscale,
    const int* __restrict__ cnt, const int* __restrict__ offs,
    const int* __restrict__ ntile_p, const int* __restrict__ wlist,
    const float* __restrict__ tw, float* __restrict__ ybuf)
{
    const int bx = blockIdx.x;
    if (bx >= *ntile_p) return;
    const int wl = wlist[bx];
    const int e = wl >> 8, mt = wl & 255;
    const int ht = blockIdx.y;
    const int count = cnt[e];
    const int t = threadIdx.x, lane = t & 63, w = t >> 6;
    const int wm = w >> 1, wn = w & 1;

    __shared__ v4i sm[2048];   // A [0,1024), B [1024,2048)
    char* smb = (char*)sm;

    const char* ga = (const char*)gbt + (size_t)bx * 458752 + lane * 16;
    const char* gb = (const char*)(w2t + (size_t)(e * 8 + ht) * 28 * 1024) + lane * 16;
    const int cid = w * 8;

    v16i acc[2][2];
#pragma unroll
    for (int i = 0; i < 2; i++)
#pragma unroll
        for (int j = 0; j < 2; j++)
#pragma unroll
            for (int r = 0; r < 16; r++) acc[i][j][r] = 0;

    for (int kt = 0; kt < 28; kt++) {
#pragma unroll
        for (int j = 0; j < 8; j++) {
            int c = cid + j;
            if (c < 16) async16(ga + (size_t)kt * 16384 + c * 1024, smb + c * 1024);
            else        async16(gb + (size_t)kt * 16384 + (c - 16) * 1024,
                                smb + 16384 + (c - 16) * 1024);
        }
        __syncthreads();
#pragma unroll
        for (int s = 0; s < 4; s++) {
            const int c16 = (2 * s + (lane >> 5)) & 3;
            const int base = (s >> 1) * 512 + c16 * 32 + (lane & 31);
            v4i a0 = sm[base + (wm * 2 + 0) * 128];
            v4i a1 = sm[base + (wm * 2 + 1) * 128];
            v4i b0 = sm[1024 + base + (wn * 2 + 0) * 128];
            v4i b1 = sm[1024 + base + (wn * 2 + 1) * 128];
            acc[0][0] = __builtin_amdgcn_mfma_i32_32x32x32_i8(a0, b0, acc[0][0], 0, 0, 0);
            acc[0][1] = __builtin_amdgcn_mfma_i32_32x32x32_i8(a0, b1, acc[0][1], 0, 0, 0);
            acc[1][0] = __builtin_amdgcn_mfma_i32_32x32x32_i8(a1, b0, acc[1][0], 0, 0, 0);
            acc[1][1] = __builtin_amdgcn_mfma_i32_32x32x32_i8(a1, b1, acc[1][1], 0, 0, 0);
        }
        __syncthreads();
    }

    const float ds = dscale[e];
    const int rowbase = offs[e] + mt * 128;
#pragma unroll
    for (int im = 0; im < 2; im++) {
#pragma unroll
        for (int in = 0; in < 2; in++) {
            const int h = ht * 128 + wn * 64 + in * 32 + (lane & 31);
            const float sc = ds * w2s[e * H_DIM + h];
#pragma unroll
            for (int r = 0; r < 16; r++) {
                int row = wm * 64 + im * 32 + (r & 3) + 8 * (r >> 2) + 4 * (lane >> 5);
                int p = mt * 128 + row;
                if (p < count) {
                    float rw = tw[e * T_TOK + p];
                    ybuf[(size_t)(rowbase + row) * H_DIM + h] = (float)acc[im][in][r] * sc * rw;
                }
            }
        }
    }
}

// ---------------- combine: out[token] = y[slot0] + y[slot1] ----------------
__global__ __launch_bounds__(256) void combine_kernel(
    const float* __restrict__ ybuf, const int* __restrict__ offs,
    const int* __restrict__ tslot, float* __restrict__ out)
{
    const int token = blockIdx.x;
    const int i = threadIdx.x;
    const int s0 = tslot[token * 2 + 0];
    const int s1 = tslot[token * 2 + 1];
    const int slot0 = offs[s0 >> 16] + (s0 & 0xffff);
    const int slot1 = offs[s1 >> 16] + (s1 & 0xffff);
    float4 a = ((const float4*)(ybuf + (size_t)slot0 * H_DIM))[i];
    float4 b = ((const float4*)(ybuf + (size_t)slot1 * H_DIM))[i];
    float4 o;
    o.x = a.x + b.x; o.y = a.y + b.y; o.z = a.z + b.z; o.w = a.w + b.w;
    ((float4*)(out + (size_t)token * H_DIM))[i] = o;
}

extern "C" void kernel_launch(void* const* d_in, const int* in_sizes, int n_in,
                              void* d_out, int out_size, void* d_ws, size_t ws_size,
                              hipStream_t stream)
{
    const float* x    = (const float*)d_in[0];
    const float* gw   = (const float*)d_in[1];
    const float* w1   = (const float*)d_in[2];
    const float* w1s  = (const float*)d_in[3];
    const float* w3   = (const float*)d_in[4];
    const float* w3s  = (const float*)d_in[5];
    const float* w2   = (const float*)d_in[6];
    const float* w2s  = (const float*)d_in[7];
    const float* dsc  = (const float*)d_in[8];

    float* out = (float*)d_out;
    float* logits_out = out + (size_t)T_TOK * H_DIM;

    char* ws = (char*)d_ws;
    v4i*    w13t = (v4i*)   (ws + W13T_OFF);
    int8_t* xq   = (int8_t*)(ws + XQ_OFF);
    v4i*    w2t  = (v4i*)   (ws + W2T_OFF);
    int8_t* gbt  = (int8_t*)(ws + GBT_OFF);
    float*  xs   = (float*) (ws + XS_OFF);
    int*    list = (int*)   (ws + LIST_OFF);
    float*  tws  = (float*) (ws + TW_OFF);
    int*    tslot= (int*)   (ws + TSLOT_OFF);
    int*    cnt  = (int*)   (ws + CNT_OFF);
    int*    offs = (int*)   (ws + OFFS_OFF);
    int*    ntile= (int*)   (ws + NT_OFF);
    int*    wlist= (int*)   (ws + WLIST_OFF);
    float*  ybuf = (float*) (ws + YBUF_OFF);

    hipMemsetAsync(cnt, 0, N_EXP * sizeof(int), stream);

    convert_kernel<<<21504, 256, 0, stream>>>(w1, w3, w2, w13t, w2t);
    router_kernel<<<T_TOK, 256, 0, stream>>>(x, gw, xq, xs, cnt, list, tws, tslot, logits_out);
    planner_kernel<<<1, 64, 0, stream>>>(cnt, offs, ntile, wlist);
    gemm1_kernel<<<dim3(136, 28), 256, 0, stream>>>(
        xq, xs, w13t, w1s, w3s, dsc, cnt, ntile, wlist, list, gbt);
    gemm2_kernel<<<dim3(136, 8), 256, 0, stream>>>(
        gbt, w2t, w2s, dsc, cnt, offs, ntile, wlist, tws, ybuf);
    combine_kernel<<<T_TOK, 256, 0, stream>>>(ybuf, offs, tslot, out);
}

// Round 4
// 928.857 us; speedup vs baseline: 1.5198x; 1.0779x over previous
//
#include <hip/hip_runtime.h>
#include <stdint.h>

typedef int v4i  __attribute__((ext_vector_type(4)));
typedef int v16i __attribute__((ext_vector_type(16)));

#define T_TOK 8192
#define H_DIM 1024
#define F_DIM 3584
#define N_EXP 8

// ---------------- workspace layout (bytes) ----------------
// BK=64 slabs: 8 KB = [rg(4)][c16(4)][r(32)] v4i; element (row=rg*32+r, k=c16*16..+16).
// Staging a slab is a LINEAR copy (wave-uniform base + lane*16).
#define W13T_OFF  0u               // [e][ft(28)][kt64(16)][mat(2)][8KB] = 58,720,256
#define XQ_OFF    58720256u        // [token][1024]                       8,388,608
#define W2T_OFF   67108864u        // [e][ht(8)][kt64(56)][8KB]          29,360,128
#define GBT_OFF   96501760u        // [tile(136)][kt64(56)][8KB]         62,390,272
#define XS_OFF    158892032u
#define LIST_OFF  158924800u
#define TW_OFF    159186944u
#define TSLOT_OFF 159449088u
#define CNT_OFF   159514624u
#define OFFS_OFF  159514656u
#define NT_OFF    159514688u
#define WLIST_OFF 159514752u
// YBUF aliases [w13t|xq] = 67,108,864 B exactly; both dead after gemm1.
#define YBUF_OFF  0u

__device__ __forceinline__ void async16(const void* g, void* l) {
    __builtin_amdgcn_global_load_lds(
        (const __attribute__((address_space(1))) unsigned int*)g,
        (__attribute__((address_space(3))) unsigned int*)l, 16, 0, 0);
}

__device__ __forceinline__ int pack4(float a, float b, float c, float d) {
    int ia = (int)(signed char)(int)a, ib = (int)(signed char)(int)b;
    int ic = (int)(signed char)(int)c, id = (int)(signed char)(int)d;
    return (ia & 0xff) | ((ib & 0xff) << 8) | ((ic & 0xff) << 16) | (id << 24);
}

// ---------------- weight fp32 -> int8 tiled repack (BK=64 slabs) ----------------
__global__ __launch_bounds__(256) void convert_kernel(
    const float* __restrict__ w1, const float* __restrict__ w3,
    const float* __restrict__ w2, v4i* __restrict__ w13t, v4i* __restrict__ w2t)
{
    const int bid = blockIdx.x;
    const float* s;
    v4i* dst;
    if (bid < 14336) {                        // w13t: 3,670,016 v4i
        int d = bid * 256 + threadIdx.x;
        int wi = d & 511;
        int rg = wi >> 7, c16 = (wi >> 5) & 3, r = wi & 31;
        int si = d >> 9;
        int mat = si & 1, kt = (si >> 1) & 15, rest = si >> 5;  // e*28+ft
        int e = rest / 28, ft = rest - e * 28;
        s = (mat ? w3 : w1)
          + ((size_t)(e * F_DIM + ft * 128 + rg * 32 + r)) * H_DIM
          + kt * 64 + c16 * 16;
        dst = w13t + d;
    } else {                                  // w2t: 1,835,008 v4i
        int d = (bid - 14336) * 256 + threadIdx.x;
        int wi = d & 511;
        int rg = wi >> 7, c16 = (wi >> 5) & 3, r = wi & 31;
        int si = d >> 9;
        int kt = si % 56, q = si / 56;
        int ht = q & 7, e = q >> 3;
        s = w2 + ((size_t)(e * H_DIM + ht * 128 + rg * 32 + r)) * F_DIM
              + kt * 64 + c16 * 16;
        dst = w2t + d;
    }
    const float4* sv = (const float4*)s;
    float4 f0 = sv[0], f1 = sv[1], f2 = sv[2], f3 = sv[3];
    v4i o;
    o.x = pack4(f0.x, f0.y, f0.z, f0.w);
    o.y = pack4(f1.x, f1.y, f1.z, f1.w);
    o.z = pack4(f2.x, f2.y, f2.z, f2.w);
    o.w = pack4(f3.x, f3.y, f3.z, f3.w);
    *dst = o;
}

// ---------------- router + per-token activation quant ----------------
__global__ __launch_bounds__(256) void router_kernel(
    const float* __restrict__ x, const float* __restrict__ gw,
    int8_t* __restrict__ xq, float* __restrict__ xs,
    int* __restrict__ cnt, int* __restrict__ list, float* __restrict__ tw,
    int* __restrict__ tslot, float* __restrict__ logits_out)
{
    const int token = blockIdx.x;
    const int t = threadIdx.x;
    __shared__ float red[256 * 8];
    __shared__ float ram[256];
    __shared__ float s_scale;

    const float4 xv = ((const float4*)(x + (size_t)token * H_DIM))[t];
    float am = fmaxf(fmaxf(fabsf(xv.x), fabsf(xv.y)), fmaxf(fabsf(xv.z), fabsf(xv.w)));
    float part[8];
#pragma unroll
    for (int e = 0; e < 8; e++) {
        const float4 g = ((const float4*)(gw + e * H_DIM))[t];
        part[e] = xv.x * g.x + xv.y * g.y + xv.z * g.z + xv.w * g.w;
    }
#pragma unroll
    for (int e = 0; e < 8; e++) red[t * 8 + e] = part[e];
    ram[t] = am;
    __syncthreads();
    for (int s = 128; s > 0; s >>= 1) {
        if (t < s) {
#pragma unroll
            for (int e = 0; e < 8; e++) red[t * 8 + e] += red[(t + s) * 8 + e];
            ram[t] = fmaxf(ram[t], ram[t + s]);
        }
        __syncthreads();
    }
    if (t == 0) {
        float l[8];
#pragma unroll
        for (int e = 0; e < 8; e++) l[e] = red[e];
        float m = l[0];
#pragma unroll
        for (int e = 1; e < 8; e++) m = fmaxf(m, l[e]);
        float p[8], sum = 0.0f;
#pragma unroll
        for (int e = 0; e < 8; e++) { p[e] = expf(l[e] - m); sum += p[e]; }
#pragma unroll
        for (int e = 0; e < 8; e++) p[e] = p[e] / sum;
        int i0 = 0;
#pragma unroll
        for (int e = 1; e < 8; e++) if (p[e] > p[i0]) i0 = e;
        int i1 = (i0 == 0) ? 1 : 0;
#pragma unroll
        for (int e = 0; e < 8; e++) if (e != i0 && p[e] > p[i1]) i1 = e;
        float tsum = p[i0] + p[i1];
        float w0 = p[i0] / tsum;
        float w1 = p[i1] / tsum;
#pragma unroll
        for (int e = 0; e < 8; e++) logits_out[(size_t)token * 8 + e] = l[e];
        int pos0 = atomicAdd(&cnt[i0], 1);
        list[i0 * T_TOK + pos0] = token;  tw[i0 * T_TOK + pos0] = w0;
        int pos1 = atomicAdd(&cnt[i1], 1);
        list[i1 * T_TOK + pos1] = token;  tw[i1 * T_TOK + pos1] = w1;
        tslot[token * 2 + 0] = (i0 << 16) | pos0;
        tslot[token * 2 + 1] = (i1 << 16) | pos1;
        s_scale = fmaxf(ram[0], 1e-8f) / 127.0f;
        xs[token] = s_scale;
    }
    __syncthreads();
    const float s = s_scale;
    char4 c;
    c.x = (signed char)fminf(fmaxf(rintf(xv.x / s), -127.0f), 127.0f);
    c.y = (signed char)fminf(fmaxf(rintf(xv.y / s), -127.0f), 127.0f);
    c.z = (signed char)fminf(fmaxf(rintf(xv.z / s), -127.0f), 127.0f);
    c.w = (signed char)fminf(fmaxf(rintf(xv.w / s), -127.0f), 127.0f);
    ((char4*)xq)[(size_t)token * (H_DIM / 4) + t] = c;
}

// ---------------- planner ----------------
__global__ void planner_kernel(const int* __restrict__ cnt, int* __restrict__ offs,
                               int* __restrict__ ntile, int* __restrict__ wlist)
{
    if (threadIdx.x == 0) {
        int s = 0, nt = 0;
        for (int e = 0; e < N_EXP; e++) {
            offs[e] = s;
            int c = cnt[e];
            s += c;
            int tc = (c + 127) >> 7;
            for (int m = 0; m < tc; m++) wlist[nt++] = (e << 8) | m;
        }
        *ntile = nt;
    }
}

// ---------------- grouped GEMM1: double-buffered pipeline, BK=64 ----------------
__global__ __launch_bounds__(256, 2) void gemm1_kernel(
    const int8_t* __restrict__ xq, const float* __restrict__ xs,
    const v4i* __restrict__ w13t,
    const float* __restrict__ w1s, const float* __restrict__ w3s,
    const float* __restrict__ dscale,
    const int* __restrict__ cnt, const int* __restrict__ ntile_p,
    const int* __restrict__ wlist, const int* __restrict__ list,
    int8_t* __restrict__ gbt)
{
    const int bx = blockIdx.x;
    if (bx >= *ntile_p) return;
    const int wl = wlist[bx];
    const int e = wl >> 8, mt = wl & 255;
    const int ft = blockIdx.y;
    const int count = cnt[e];
    const int t = threadIdx.x, lane = t & 63, w = t >> 6;
    const int wm = w >> 1, wn = w & 1;
    const int* liste = list + e * T_TOK;

    __shared__ v4i sm[3072];   // 2 buffers x [A 512 | B1 512 | B3 512] v4i
    char* smb = (char*)sm;

    const int cm1 = count - 1;
    const int pA = mt * 128 + w * 32 + (lane & 31);
    const int tokA = liste[pA < count ? pA : cm1];
    const int8_t* gA = xq + (size_t)tokA * H_DIM + ((lane >> 5) << 4);
    const char* gB = (const char*)(w13t + (size_t)(e * 28 + ft) * 16384) + lane * 16;
    const int wq = w * 2048;

    v16i acc1[2][2], acc3[2][2];
#pragma unroll
    for (int i = 0; i < 2; i++)
#pragma unroll
        for (int j = 0; j < 2; j++)
#pragma unroll
            for (int r = 0; r < 16; r++) { acc1[i][j][r] = 0; acc3[i][j][r] = 0; }

    auto stage = [&](int kt, int buf) {
        char* base = smb + buf * 24576;
        const int ko = kt * 64;
        async16(gA + ko,      base + wq);
        async16(gA + ko + 32, base + wq + 1024);
        const char* s1 = gB + (size_t)kt * 16384;
        async16(s1 + wq,               base + 8192 + wq);
        async16(s1 + wq + 1024,        base + 8192 + wq + 1024);
        async16(s1 + 8192 + wq,        base + 16384 + wq);
        async16(s1 + 8192 + wq + 1024, base + 16384 + wq + 1024);
    };
    auto compute = [&](int buf) {
        const v4i* S = sm + buf * 1536;
#pragma unroll
        for (int ks = 0; ks < 2; ks++) {
            const int base = (2 * ks + (lane >> 5)) * 32 + (lane & 31);
            v4i a0  = S[base + (wm * 2 + 0) * 128];
            v4i a1  = S[base + (wm * 2 + 1) * 128];
            v4i b1a = S[512 + base + (wn * 2 + 0) * 128];
            v4i b1b = S[512 + base + (wn * 2 + 1) * 128];
            v4i b3a = S[1024 + base + (wn * 2 + 0) * 128];
            v4i b3b = S[1024 + base + (wn * 2 + 1) * 128];
            acc1[0][0] = __builtin_amdgcn_mfma_i32_32x32x32_i8(a0, b1a, acc1[0][0], 0, 0, 0);
            acc1[0][1] = __builtin_amdgcn_mfma_i32_32x32x32_i8(a0, b1b, acc1[0][1], 0, 0, 0);
            acc1[1][0] = __builtin_amdgcn_mfma_i32_32x32x32_i8(a1, b1a, acc1[1][0], 0, 0, 0);
            acc1[1][1] = __builtin_amdgcn_mfma_i32_32x32x32_i8(a1, b1b, acc1[1][1], 0, 0, 0);
            acc3[0][0] = __builtin_amdgcn_mfma_i32_32x32x32_i8(a0, b3a, acc3[0][0], 0, 0, 0);
            acc3[0][1] = __builtin_amdgcn_mfma_i32_32x32x32_i8(a0, b3b, acc3[0][1], 0, 0, 0);
            acc3[1][0] = __builtin_amdgcn_mfma_i32_32x32x32_i8(a1, b3a, acc3[1][0], 0, 0, 0);
            acc3[1][1] = __builtin_amdgcn_mfma_i32_32x32x32_i8(a1, b3b, acc3[1][1], 0, 0, 0);
        }
    };

    stage(0, 0);
    for (int kt = 0; kt < 16; kt++) {
        __syncthreads();               // drains stage(kt); confirms reads of other buf done
        if (kt + 1 < 16) stage(kt + 1, (kt + 1) & 1);
        compute(kt & 1);
    }

    const float ds = dscale[e];
    // write gemm2 A-slabs: tile bx, kt2 = ft*2 + wn
    int8_t* gout = gbt + (size_t)bx * 458752 + (size_t)(ft * 2 + wn) * 8192;
#pragma unroll
    for (int im = 0; im < 2; im++) {
#pragma unroll
        for (int in = 0; in < 2; in++) {
            const int fco = in * 32 + (lane & 31);          // k-offset within 64
            const int fcol = ft * 128 + wn * 64 + fco;
            const float s1 = w1s[e * F_DIM + fcol];
            const float s3 = w3s[e * F_DIM + fcol];
            const int coff = ((in * 2 + ((lane & 31) >> 4)) * 32) * 16 + (lane & 15);
#pragma unroll
            for (int r = 0; r < 16; r++) {
                int row = wm * 64 + im * 32 + (r & 3) + 8 * (r >> 2) + 4 * (lane >> 5);
                int p = mt * 128 + row;
                if (p < count) {
                    int token = liste[p];
                    float sx = xs[token];
                    float h1 = (float)acc1[im][in][r] * sx * s1;
                    float h3 = (float)acc3[im][in][r] * sx * s3;
                    float g = (h1 / (1.0f + expf(-h1))) * h3;
                    float qv = fminf(fmaxf(rintf(g / ds), -127.0f), 127.0f);
                    gout[(size_t)((wm * 2 + im) * 128 + (row & 31)) * 16 + coff] = (int8_t)qv;
                }
            }
        }
    }
}

// ---------------- grouped GEMM2: double-buffered pipeline, BK=64 ----------------
__global__ __launch_bounds__(256, 3) void gemm2_kernel(
    const int8_t* __restrict__ gbt, const v4i* __restrict__ w2t,
    const float* __restrict__ w2s, const float* __restrict__ dscale,
    const int* __restrict__ cnt, const int* __restrict__ offs,
    const int* __restrict__ ntile_p, const int* __restrict__ wlist,
    const float* __restrict__ tw, float* __restrict__ ybuf)
{
    const int bx = blockIdx.x;
    if (bx >= *ntile_p) return;
    const int wl = wlist[bx];
    const int e = wl >> 8, mt = wl & 255;
    const int ht = blockIdx.y;
    const int count = cnt[e];
    const int t = threadIdx.x, lane = t & 63, w = t >> 6;
    const int wm = w >> 1, wn = w & 1;

    __shared__ v4i sm[2048];   // 2 buffers x [A 512 | B 512]
    char* smb = (char*)sm;

    const char* gA = (const char*)gbt + (size_t)bx * 458752 + w * 2048 + lane * 16;
    const char* gB = (const char*)(w2t + (size_t)(e * 8 + ht) * 28672) + w * 2048 + lane * 16;

    v16i acc[2][2];
#pragma unroll
    for (int i = 0; i < 2; i++)
#pragma unroll
        for (int j = 0; j < 2; j++)
#pragma unroll
            for (int r = 0; r < 16; r++) acc[i][j][r] = 0;

    auto stage = [&](int kt, int buf) {
        char* base = smb + buf * 16384;
        const size_t ko = (size_t)kt * 8192;
        async16(gA + ko,        base + w * 2048);
        async16(gA + ko + 1024, base + w * 2048 + 1024);
        async16(gB + ko,        base + 8192 + w * 2048);
        async16(gB + ko + 1024, base + 8192 + w * 2048 + 1024);
    };
    auto compute = [&](int buf) {
        const v4i* S = sm + buf * 1024;
#pragma unroll
        for (int ks = 0; ks < 2; ks++) {
            const int base = (2 * ks + (lane >> 5)) * 32 + (lane & 31);
            v4i a0 = S[base + (wm * 2 + 0) * 128];
            v4i a1 = S[base + (wm * 2 + 1) * 128];
            v4i b0 = S[512 + base + (wn * 2 + 0) * 128];
            v4i b1 = S[512 + base + (wn * 2 + 1) * 128];
            acc[0][0] = __builtin_amdgcn_mfma_i32_32x32x32_i8(a0, b0, acc[0][0], 0, 0, 0);
            acc[0][1] = __builtin_amdgcn_mfma_i32_32x32x32_i8(a0, b1, acc[0][1], 0, 0, 0);
            acc[1][0] = __builtin_amdgcn_mfma_i32_32x32x32_i8(a1, b0, acc[1][0], 0, 0, 0);
            acc[1][1] = __builtin_amdgcn_mfma_i32_32x32x32_i8(a1, b1, acc[1][1], 0, 0, 0);
        }
    };

    stage(0, 0);
    for (int kt = 0; kt < 56; kt++) {
        __syncthreads();
        if (kt + 1 < 56) stage(kt + 1, (kt + 1) & 1);
        compute(kt & 1);
    }

    const float ds = dscale[e];
    const int rowbase = offs[e] + mt * 128;
#pragma unroll
    for (int im = 0; im < 2; im++) {
#pragma unroll
        for (int in = 0; in < 2; in++) {
            const int h = ht * 128 + wn * 64 + in * 32 + (lane & 31);
            const float sc = ds * w2s[e * H_DIM + h];
#pragma unroll
            for (int r = 0; r < 16; r++) {
                int row = wm * 64 + im * 32 + (r & 3) + 8 * (r >> 2) + 4 * (lane >> 5);
                int p = mt * 128 + row;
                if (p < count) {
                    float rw = tw[e * T_TOK + p];
                    ybuf[(size_t)(rowbase + row) * H_DIM + h] = (float)acc[im][in][r] * sc * rw;
                }
            }
        }
    }
}

// ---------------- combine ----------------
__global__ __launch_bounds__(256) void combine_kernel(
    const float* __restrict__ ybuf, const int* __restrict__ offs,
    const int* __restrict__ tslot, float* __restrict__ out)
{
    const int token = blockIdx.x;
    const int i = threadIdx.x;
    const int s0 = tslot[token * 2 + 0];
    const int s1 = tslot[token * 2 + 1];
    const int slot0 = offs[s0 >> 16] + (s0 & 0xffff);
    const int slot1 = offs[s1 >> 16] + (s1 & 0xffff);
    float4 a = ((const float4*)(ybuf + (size_t)slot0 * H_DIM))[i];
    float4 b = ((const float4*)(ybuf + (size_t)slot1 * H_DIM))[i];
    float4 o;
    o.x = a.x + b.x; o.y = a.y + b.y; o.z = a.z + b.z; o.w = a.w + b.w;
    ((float4*)(out + (size_t)token * H_DIM))[i] = o;
}

extern "C" void kernel_launch(void* const* d_in, const int* in_sizes, int n_in,
                              void* d_out, int out_size, void* d_ws, size_t ws_size,
                              hipStream_t stream)
{
    const float* x    = (const float*)d_in[0];
    const float* gw   = (const float*)d_in[1];
    const float* w1   = (const float*)d_in[2];
    const float* w1s  = (const float*)d_in[3];
    const float* w3   = (const float*)d_in[4];
    const float* w3s  = (const float*)d_in[5];
    const float* w2   = (const float*)d_in[6];
    const float* w2s  = (const float*)d_in[7];
    const float* dsc  = (const float*)d_in[8];

    float* out = (float*)d_out;
    float* logits_out = out + (size_t)T_TOK * H_DIM;

    char* ws = (char*)d_ws;
    v4i*    w13t = (v4i*)   (ws + W13T_OFF);
    int8_t* xq   = (int8_t*)(ws + XQ_OFF);
    v4i*    w2t  = (v4i*)   (ws + W2T_OFF);
    int8_t* gbt  = (int8_t*)(ws + GBT_OFF);
    float*  xs   = (float*) (ws + XS_OFF);
    int*    list = (int*)   (ws + LIST_OFF);
    float*  tws  = (float*) (ws + TW_OFF);
    int*    tslot= (int*)   (ws + TSLOT_OFF);
    int*    cnt  = (int*)   (ws + CNT_OFF);
    int*    offs = (int*)   (ws + OFFS_OFF);
    int*    ntile= (int*)   (ws + NT_OFF);
    int*    wlist= (int*)   (ws + WLIST_OFF);
    float*  ybuf = (float*) (ws + YBUF_OFF);

    hipMemsetAsync(cnt, 0, N_EXP * sizeof(int), stream);

    convert_kernel<<<21504, 256, 0, stream>>>(w1, w3, w2, w13t, w2t);
    router_kernel<<<T_TOK, 256, 0, stream>>>(x, gw, xq, xs, cnt, list, tws, tslot, logits_out);
    planner_kernel<<<1, 64, 0, stream>>>(cnt, offs, ntile, wlist);
    gemm1_kernel<<<dim3(136, 28), 256, 0, stream>>>(
        xq, xs, w13t, w1s, w3s, dsc, cnt, ntile, wlist, list, gbt);
    gemm2_kernel<<<dim3(136, 8), 256, 0, stream>>>(
        gbt, w2t, w2s, dsc, cnt, offs, ntile, wlist, tws, ybuf);
    combine_kernel<<<T_TOK, 256, 0, stream>>>(ybuf, offs, tslot, out);
}